// Round 18
// baseline (39.836 us; speedup 1.0000x reference)
//
#include <hip/hip_runtime.h>

#define N_IN   4096
#define N_OUT  4082      // 4096 - 15 + 1
#define KS     15
#define TILE_R 16        // output rows per wave-tile
#define TILE_C 64        // output cols per wave-tile
#define PRW    30        // patch rows per tile (16 + 14)
#define PCW    80        // patch cols per tile (64 + 16)
#define C4W    20        // float4 chunks per patch row
#define WITEMS (PRW * C4W)         // 600 staging items per tile
#define NTC    64        // col tiles  (ceil(4082/64))
#define NTR    256       // row bands  (ceil(4082/16))

// R18: wave-autonomous tiles, ZERO barriers. Measured facts driving this:
// (1) hipcc pins this kernel family at 64 arch-VGPRs (R10/14/15/16/17 —
//     every >64-demand structure spilled; waves_per_eu didn't help);
// (2) the 512-thr barrier-coupled structure plateaued 35-39us at 16 waves/CU
//     with no pipe >50% (latency-bound).
// So: design TO 64 regs and raise TLP. Each wave owns one 16x64 tile:
// stage own 30x80 patch (4.8KB LDS slice, fp32->bf16) -> lgkmcnt(0) +
// sched_barrier(0) (rule #18; wave-coherent, no __syncthreads) -> 8
// shared-window pairs (5 A ds_read_b128 + 2 B global L1-hot) -> 64 MFMAs.
// 256-thr blocks x 19.2KB LDS -> 8 blocks/CU = 32 waves/CU (2x R11's TLP).
// Reg ledger: staging 24 | compute 28+16 (phases disjoint) + addr ~10 < 64.
// Halo cost: 1.875x row refetch; ~2048 resident blocks -> band neighbors
// concurrent -> L2/L3 absorb. XCD-chunked swizzle: one XCD's 512-block run
// spans ~8 bands ~= 3.9MB source rows ~= its 4MB L2.
// Bank: pitch 80 bf16 = 40 words == 8 mod 32 -> (2m + parity) spread, 8
// lanes/quad = b128 floor (same pattern family measured 0-conflict R6-R17).

typedef __attribute__((ext_vector_type(8))) short bf16x8;
typedef __attribute__((ext_vector_type(4))) float f32x4;

__device__ inline unsigned short f2bf(float f) {   // round-to-nearest-even
    unsigned u = __builtin_bit_cast(unsigned, f);
    u += 0x7FFFu + ((u >> 16) & 1u);
    return (unsigned short)(u >> 16);
}
__device__ inline ushort4 f2bf4(float4 v) {
    ushort4 b; b.x = f2bf(v.x); b.y = f2bf(v.y); b.z = f2bf(v.z); b.w = f2bf(v.w);
    return b;
}

#define MF(a, b, c) __builtin_amdgcn_mfma_f32_16x16x32_bf16((a), (b), (c), 0, 0, 0)

// ---- pre-kernel: build the 16-entry B table in global ws (verified R13) ----
// entry idx = P*2+h: B[k=16p'+q'][n=m] = wpad[2P+p'][q' + 16h - m]
__global__ __launch_bounds__(64) void btab_fill_kernel(
    const float* __restrict__ w, unsigned short* __restrict__ bt)
{
    const int idx  = blockIdx.x;          // 0..15
    const int lane = threadIdx.x;         // 0..63
    const int P  = idx >> 1, h = idx & 1;
    const int m  = lane & 15;
    const int g  = lane >> 4;
    const int gp = g >> 1, g1 = g & 1;
    bf16x8 f;
    #pragma unroll
    for (int e = 0; e < 8; ++e) {
        const int prow = 2 * P + gp;
        const int col  = g1 * 8 + e + 16 * h - m;
        const float vv = (prow < KS && col >= 0 && col < KS) ? w[prow * KS + col] : 0.f;
        f[e] = (short)f2bf(vv);
    }
    *reinterpret_cast<bf16x8*>(&bt[idx * 512 + lane * 8]) = f;
}

// one staging item (j-th round): patch row = it/C4W, col4 = it%C4W
#define WISSUE(j, v) {                                                    \
    const int _it  = lane + 64 * (j);                                     \
    const int _row = _it / C4W;                                           \
    const int _c4  = _it % C4W;                                           \
    const int _gr  = r0 + _row;                                           \
    const int _gc  = c0 + _c4 * 4;                                        \
    if (_gr < N_IN && _gc < N_IN)                                         \
        v = *reinterpret_cast<const float4*>(&x[_gr * N_IN + _gc]);       \
}
#define WCOMMIT(j, v) {                                                   \
    const int _it  = lane + 64 * (j);                                     \
    const int _row = _it / C4W;                                           \
    const int _c4  = _it % C4W;                                           \
    *reinterpret_cast<ushort4*>(&myl[_row * PCW + _c4 * 4]) = f2bf4(v);   \
}

__global__ __launch_bounds__(256, 8) void Conv2DScratch_82025285419642_kernel(
    const float* __restrict__ x, const unsigned short* __restrict__ btab,
    const float* __restrict__ bias, float* __restrict__ out)
{
    __shared__ unsigned short xs[4 * PRW * PCW];   // 4 waves x 4800 B = 19,200 B

    const int tid  = threadIdx.x;
    const int lane = tid & 63;
    const int wv   = tid >> 6;            // 0..3 : wave picks its own tile
    const int m    = lane & 15;           // A row within tile / D col
    const int g    = lane >> 4;           // k-group / D row group
    const int gp   = g >> 1;              // p' within pair
    const int g1   = g & 1;               // q' high/low 8

    // XCD-chunked bijective swizzle (4096 blocks, 8 XCDs, 512 each):
    // one XCD gets a contiguous run of tiles (col-major within row-band)
    const int bid  = blockIdx.x;
    const int s    = ((bid & 7) << 9) | (bid >> 3);
    const int tile = s * 4 + wv;          // 0..16383
    const int band = tile >> 6;           // row band 0..255
    const int ct   = tile & 63;           // col tile 0..63
    const int r0   = band * TILE_R;
    const int c0   = ct * TILE_C;

    unsigned short* myl = &xs[wv * (PRW * PCW)];   // this wave's 4.8KB slice

    // ---- per-wave staging: 600 items in 6-reg rotation (24 live regs) ----
    float4 s0 = make_float4(0.f,0.f,0.f,0.f), s1 = s0, s2 = s0,
           s3 = s0, s4 = s0, s5 = s0;
    WISSUE(0, s0) WISSUE(1, s1) WISSUE(2, s2)
    WISSUE(3, s3) WISSUE(4, s4) WISSUE(5, s5)
    const float b0 = bias[0];
    WCOMMIT(0, s0) WCOMMIT(1, s1) WCOMMIT(2, s2)
    s0 = make_float4(0.f,0.f,0.f,0.f); s1 = s0; s2 = s0;
    WISSUE(6, s0) WISSUE(7, s1) WISSUE(8, s2)
    WCOMMIT(3, s3) WCOMMIT(4, s4) WCOMMIT(5, s5)
    s3 = make_float4(0.f,0.f,0.f,0.f);
    if (lane < WITEMS - 576) WISSUE(9, s3)         // 24-item tail
    WCOMMIT(6, s0) WCOMMIT(7, s1) WCOMMIT(8, s2)
    if (lane < WITEMS - 576) WCOMMIT(9, s3)

    // wave-coherent LDS: drain DS queue, fence the scheduler (rule #18)
    asm volatile("s_waitcnt lgkmcnt(0)" ::: "memory");
    __builtin_amdgcn_sched_barrier(0);

    // ---- compute: 8 pairs, 5 shared A-windows + 2 B-frags -> 8 MFMAs each ----
    const unsigned char* mylb = (const unsigned char*)myl;
    const unsigned char* btb  = (const unsigned char*)btab;
    const int cb0    = 16 * g1;           // A-read byte offset within patch row
    const int lane16 = lane * 16;

    f32x4 acc0 = {0.f,0.f,0.f,0.f}, acc1 = acc0, acc2 = acc0, acc3 = acc0;

    #define PPAIR(ROW, Pb) {                                              \
        const unsigned char* _ab = mylb + (ROW) * (PCW * 2) + cb0;        \
        const bf16x8 a0 = *reinterpret_cast<const bf16x8*>(_ab +   0);    \
        const bf16x8 a1 = *reinterpret_cast<const bf16x8*>(_ab +  32);    \
        const bf16x8 a2 = *reinterpret_cast<const bf16x8*>(_ab +  64);    \
        const bf16x8 a3 = *reinterpret_cast<const bf16x8*>(_ab +  96);    \
        const bf16x8 a4 = *reinterpret_cast<const bf16x8*>(_ab + 128);    \
        const bf16x8 bl = *reinterpret_cast<const bf16x8*>(               \
            btb + (Pb) * 2048 + lane16);                                  \
        const bf16x8 bh = *reinterpret_cast<const bf16x8*>(               \
            btb + (Pb) * 2048 + 1024 + lane16);                           \
        acc0 = MF(a0, bl, acc0); acc0 = MF(a1, bh, acc0);                 \
        acc1 = MF(a1, bl, acc1); acc1 = MF(a2, bh, acc1);                 \
        acc2 = MF(a2, bl, acc2); acc2 = MF(a3, bh, acc2);                 \
        acc3 = MF(a3, bl, acc3); acc3 = MF(a4, bh, acc3);                 \
    }

    const int rbg = m + gp;               // A row base within patch (pairs 0-6)
    PPAIR(rbg +  0, 0)
    PPAIR(rbg +  2, 1)
    PPAIR(rbg +  4, 2)
    PPAIR(rbg +  6, 3)
    PPAIR(rbg +  8, 4)
    PPAIR(rbg + 10, 5)
    PPAIR(rbg + 12, 6)
    PPAIR(m + 14,   7)                    // pair 7: row 15 zero-padded in B
    #undef PPAIR

    // ---- stores: D col = m, row = g*4 + r (verified layout) ----
    const int ocb = c0 + m;
    const int or0 = r0 + g * 4;
    #define STORE_TILE(t, a) {                                            \
        const int _oc = ocb + (t) * 16;                                   \
        if (_oc < N_OUT) {                                                \
            _Pragma("unroll")                                             \
            for (int r = 0; r < 4; ++r) {                                 \
                if (or0 + r < N_OUT)                                      \
                    out[(or0 + r) * N_OUT + _oc] = a[r] + b0;             \
            }                                                             \
        }                                                                 \
    }
    STORE_TILE(0, acc0) STORE_TILE(1, acc1)
    STORE_TILE(2, acc2) STORE_TILE(3, acc3)
    #undef STORE_TILE
}

extern "C" void kernel_launch(void* const* d_in, const int* in_sizes, int n_in,
                              void* d_out, int out_size, void* d_ws, size_t ws_size,
                              hipStream_t stream) {
    const float* x    = (const float*)d_in[0];
    const float* w    = (const float*)d_in[1];
    const float* bias = (const float*)d_in[2];
    float* out        = (float*)d_out;
    unsigned short* bt = (unsigned short*)d_ws;     // 16 KB B-table

    btab_fill_kernel<<<dim3(16), dim3(64), 0, stream>>>(w, bt);

    dim3 block(256);
    dim3 grid(4096);   // 16384 wave-tiles / 4 waves per block; swizzled in-kernel
    Conv2DScratch_82025285419642_kernel<<<grid, block, 0, stream>>>(
        x, bt, bias, out);
}